// Round 1
// baseline (902.580 us; speedup 1.0000x reference)
//
#include <hip/hip_runtime.h>

// ---------- types & helpers ----------
typedef __bf16 bf16x8 __attribute__((ext_vector_type(8)));
typedef float f32x4 __attribute__((ext_vector_type(4)));

__device__ __forceinline__ float bf2f(unsigned short u) {
  union { unsigned int i; float f; } c; c.i = ((unsigned int)u) << 16; return c.f;
}
__device__ __forceinline__ unsigned short f2bf(float f) {
  union { float f; unsigned int i; } c; c.f = f;
  unsigned int u = c.i;
  u += 0x7FFFu + ((u >> 16) & 1u);   // RNE
  return (unsigned short)(u >> 16);
}

#define GLDS16(g, l)                                                          \
  __builtin_amdgcn_global_load_lds(                                           \
      (const __attribute__((address_space(1))) void*)(g),                     \
      (__attribute__((address_space(3))) void*)(l), 16, 0, 0)

// ---------- constants ----------
// B=8192, D=1024, H=4, hd=256, C=4
// ws layout (bytes):
//  Xcat  bf16 [32768 x 1024]            @ 0          (64 MB)
//  Wcat  bf16 [4096 x 1024]             @ 67108864   (8 MB)  rows: [Wk_c | Wv_c | Wq | Wv_s]
//  Wocat bf16 [1024 x 2048]             @ 75497472   (4 MB)  row n = [Wo_c[n,:], Wo_s[n,:]]
//  biaso f32  [1024]                    @ 79691776
//  Yproj bf16 [32768 x 4096]            @ 79695872   (256 MB) cols: [KcX | VcX | QX->A | VsX]

// ---------- convert X1..X4 -> bf16 Xcat ----------
__global__ __launch_bounds__(256) void convert_x(
    const float* __restrict__ X1, const float* __restrict__ X2,
    const float* __restrict__ X3, const float* __restrict__ X4,
    unsigned short* __restrict__ Xcat)
{
  int gid = blockIdx.x * 256 + threadIdx.x;          // 8388608 threads
  size_t base = (size_t)gid * 4;
  int sec = (int)(base >> 23);
  int off = (int)(base & 8388607);
  const float* s = sec == 0 ? X1 : sec == 1 ? X2 : sec == 2 ? X3 : X4;
  float4 v = *(const float4*)(s + off);
  ushort4 o;
  o.x = f2bf(v.x); o.y = f2bf(v.y); o.z = f2bf(v.z); o.w = f2bf(v.w);
  *(ushort4*)(Xcat + base) = o;
}

// ---------- prep weights ----------
__global__ __launch_bounds__(256) void prep_w(
    const float* __restrict__ Wq,  const float* __restrict__ Wk_c,
    const float* __restrict__ Wv_c, const float* __restrict__ Wv_s,
    const float* __restrict__ Wo_c, const float* __restrict__ Wo_s,
    const float* __restrict__ bo_c, const float* __restrict__ bo_s,
    unsigned short* __restrict__ Wcat, unsigned short* __restrict__ Wocat,
    float* __restrict__ biaso)
{
  int gid = blockIdx.x * 256 + threadIdx.x;
  if (gid < 1048576) {                               // Wcat: 4 x 1M elements
    int base = gid * 4;
    int sec = base >> 20, off = base & 1048575;
    const float* s = sec == 0 ? Wk_c : sec == 1 ? Wv_c : sec == 2 ? Wq : Wv_s;
    float4 v = *(const float4*)(s + off);
    ushort4 o;
    o.x = f2bf(v.x); o.y = f2bf(v.y); o.z = f2bf(v.z); o.w = f2bf(v.w);
    *(ushort4*)(Wcat + base) = o;
  } else if (gid < 1572864) {                        // Wocat: 2M elements
    int base = (gid - 1048576) * 4;
    int n = base >> 11, c = base & 2047;
    const float* s = (c < 1024) ? (Wo_c + n * 1024 + c) : (Wo_s + n * 1024 + (c - 1024));
    float4 v = *(const float4*)s;
    ushort4 o;
    o.x = f2bf(v.x); o.y = f2bf(v.y); o.z = f2bf(v.z); o.w = f2bf(v.w);
    *(ushort4*)(Wocat + base) = o;
  } else if (gid < 1573120) {                        // biaso: 1024 floats
    int i = (gid - 1572864) * 4;
    float4 a = *(const float4*)(bo_c + i);
    float4 b = *(const float4*)(bo_s + i);
    float4 r; r.x = a.x + b.x; r.y = a.y + b.y; r.z = a.z + b.z; r.w = a.w + b.w;
    *(float4*)(biaso + i) = r;
  }
}

// ---------- GEMM: C[M,N] = A[M,K(lda)] * Bw[N,K(ldb)]^T (+bias) ----------
// 128x128 block tile, BK=32, 256 threads = 4 waves (2x2), 4x4 MFMA 16x16x32 each.
// XOR swizzle on 16B k-chunks: phys_chunk = kchunk ^ ((row>>1)&3)  -> 2-way LDS conflicts max.
template<bool OUT_F32, bool HAS_BIAS>
__global__ __launch_bounds__(256) void gemm_bt(
    const unsigned short* __restrict__ A, int lda,
    const unsigned short* __restrict__ Bw, int ldb,
    void* __restrict__ Cout, int ldc,
    const float* __restrict__ bias, int K)
{
  __shared__ char lds[16384];
  char* ldsA = lds;
  char* ldsB = lds + 8192;

  const int t = threadIdx.x;
  const int l = t & 63;
  const int wv = t >> 6;
  const int wr = wv >> 1, wc = wv & 1;
  const int bM = blockIdx.y * 128, bN = blockIdx.x * 128;

  // staging: 512 16B-chunks per operand tile (128 rows x 4 chunks), 2 insts x 256 thr
  const int pa0 = t, pa1 = t + 256;
  const int ra0 = pa0 >> 2, ra1 = pa1 >> 2;
  const int ca0 = (((pa0 & 3) ^ ((ra0 >> 1) & 3))) * 8;  // element offset in k
  const int ca1 = (((pa1 & 3) ^ ((ra1 >> 1) & 3))) * 8;
  const unsigned short* gA0 = A + (size_t)(bM + ra0) * lda + ca0;
  const unsigned short* gA1 = A + (size_t)(bM + ra1) * lda + ca1;
  const unsigned short* gB0 = Bw + (size_t)(bN + ra0) * ldb + ca0;
  const unsigned short* gB1 = Bw + (size_t)(bN + ra1) * ldb + ca1;
  char* lA0 = ldsA + pa0 * 16; char* lA1 = ldsA + pa1 * 16;
  char* lB0 = ldsB + pa0 * 16; char* lB1 = ldsB + pa1 * 16;

  // fragment read addressing
  const int rA = wr * 64 + (l & 15);
  const int rB = wc * 64 + (l & 15);
  const int cA = ((l >> 4) ^ ((rA >> 1) & 3)) * 16;   // byte offset within row
  const int cB = ((l >> 4) ^ ((rB >> 1) & 3)) * 16;
  const char* fA = ldsA + rA * 64 + cA;
  const char* fB = ldsB + rB * 64 + cB;

  f32x4 acc[4][4] = {};

  for (int k0 = 0; k0 < K; k0 += 32) {
    GLDS16(gA0, lA0); GLDS16(gA1, lA1);
    GLDS16(gB0, lB0); GLDS16(gB1, lB1);
    gA0 += 32; gA1 += 32; gB0 += 32; gB1 += 32;
    __syncthreads();

    bf16x8 af[4], bf[4];
#pragma unroll
    for (int i = 0; i < 4; ++i) af[i] = *(const bf16x8*)(fA + i * 1024);
#pragma unroll
    for (int i = 0; i < 4; ++i) bf[i] = *(const bf16x8*)(fB + i * 1024);
#pragma unroll
    for (int mt = 0; mt < 4; ++mt)
#pragma unroll
      for (int nt = 0; nt < 4; ++nt)
        acc[mt][nt] = __builtin_amdgcn_mfma_f32_16x16x32_bf16(
            af[mt], bf[nt], acc[mt][nt], 0, 0, 0);
    __syncthreads();
  }

  // epilogue: D row = (lane>>4)*4 + reg, col = lane&15  (verified m89/m91 layout)
  const int mrow = bM + wr * 64 + ((l >> 4) << 2);
  const int ncol = bN + wc * 64 + (l & 15);
  float bvals[4];
  if (HAS_BIAS) {
#pragma unroll
    for (int nt = 0; nt < 4; ++nt) bvals[nt] = bias[ncol + nt * 16];
  }
#pragma unroll
  for (int mt = 0; mt < 4; ++mt)
#pragma unroll
    for (int nt = 0; nt < 4; ++nt)
#pragma unroll
      for (int r = 0; r < 4; ++r) {
        size_t idx = (size_t)(mrow + mt * 16 + r) * ldc + (ncol + nt * 16);
        float v = acc[mt][nt][r];
        if (HAS_BIAS) v += bvals[nt];
        if (OUT_F32) ((float*)Cout)[idx] = v;
        else         ((unsigned short*)Cout)[idx] = f2bf(v);
      }
}

// ---------- attention (3 keys, 4 heads) ----------
// One block per b; wave = head; lane covers 4 contiguous dims of the head slice.
// Writes attn output over the QX slot; adds bv_s into VsX slot in place.
__global__ __launch_bounds__(256) void attn_kernel(
    unsigned short* __restrict__ Yp,
    const float* __restrict__ bq,  const float* __restrict__ bkc,
    const float* __restrict__ bvc, const float* __restrict__ bvs)
{
  const int b = blockIdx.x;
  const int h = threadIdx.x >> 6;
  const int l = threadIdx.x & 63;
  const int e0 = h * 256 + l * 4;

  const float4 bqv = *(const float4*)(bq + e0);
  const float4 bkv = *(const float4*)(bkc + e0);
  const float4 bvv = *(const float4*)(bvc + e0);
  const float4 bsv = *(const float4*)(bvs + e0);

  float q[4][4], kc[4][4], vc[4][4];
  size_t rb[4];
#pragma unroll
  for (int i = 0; i < 4; ++i) {
    rb[i] = ((size_t)i * 8192 + b) * 4096;
    ushort4 qq = *(const ushort4*)(Yp + rb[i] + 2048 + e0);
    ushort4 kk = *(const ushort4*)(Yp + rb[i] + e0);
    ushort4 vv = *(const ushort4*)(Yp + rb[i] + 1024 + e0);
    q[i][0] = bf2f(qq.x) + bqv.x; q[i][1] = bf2f(qq.y) + bqv.y;
    q[i][2] = bf2f(qq.z) + bqv.z; q[i][3] = bf2f(qq.w) + bqv.w;
    kc[i][0] = bf2f(kk.x); kc[i][1] = bf2f(kk.y);
    kc[i][2] = bf2f(kk.z); kc[i][3] = bf2f(kk.w);
    vc[i][0] = bf2f(vv.x); vc[i][1] = bf2f(vv.y);
    vc[i][2] = bf2f(vv.z); vc[i][3] = bf2f(vv.w);
  }

  // partial dots: u[i][j] = Qi . KcXj  (head slice), tb[i] = Qi . bk_c
  float u[4][4], tb[4];
#pragma unroll
  for (int i = 0; i < 4; ++i) {
    tb[i] = q[i][0]*bkv.x + q[i][1]*bkv.y + q[i][2]*bkv.z + q[i][3]*bkv.w;
#pragma unroll
    for (int j = 0; j < 4; ++j)
      u[i][j] = q[i][0]*kc[j][0] + q[i][1]*kc[j][1] + q[i][2]*kc[j][2] + q[i][3]*kc[j][3];
  }
#pragma unroll
  for (int d = 1; d < 64; d <<= 1) {
#pragma unroll
    for (int i = 0; i < 4; ++i) {
      tb[i] += __shfl_xor(tb[i], d);
#pragma unroll
      for (int j = 0; j < 4; ++j) u[i][j] += __shfl_xor(u[i][j], d);
    }
  }

#pragma unroll
  for (int i = 0; i < 4; ++i) {
    // scores over the 3 other inputs: s_ij = (Qi.Kci - Qi.Kcj + Qi.bk) / 16
    float s[4], a[4];
    float mx = -1e30f;
#pragma unroll
    for (int j = 0; j < 4; ++j) {
      s[j] = (u[i][i] - u[i][j] + tb[i]) * 0.0625f;
      if (j != i) mx = fmaxf(mx, s[j]);
    }
    float den = 0.f;
#pragma unroll
    for (int j = 0; j < 4; ++j) {
      a[j] = (j == i) ? 0.f : __expf(s[j] - mx);
      den += a[j];
    }
    float inv = 1.f / den;
#pragma unroll
    for (int j = 0; j < 4; ++j) a[j] *= inv;

    // out = Vc_i + bv_c - sum_j a_j * Vc_j     (since sum a = 1)
    float o0 = vc[i][0] + bvv.x, o1 = vc[i][1] + bvv.y;
    float o2 = vc[i][2] + bvv.z, o3 = vc[i][3] + bvv.w;
#pragma unroll
    for (int j = 0; j < 4; ++j) {
      o0 -= a[j] * vc[j][0]; o1 -= a[j] * vc[j][1];
      o2 -= a[j] * vc[j][2]; o3 -= a[j] * vc[j][3];
    }
    ushort4 w;
    w.x = f2bf(o0); w.y = f2bf(o1); w.z = f2bf(o2); w.w = f2bf(o3);
    *(ushort4*)(Yp + rb[i] + 2048 + e0) = w;   // overwrite Q slot (same thread owns it)
  }

  // VsX += bv_s (in place)
#pragma unroll
  for (int i = 0; i < 4; ++i) {
    ushort4 sv = *(const ushort4*)(Yp + rb[i] + 3072 + e0);
    ushort4 w;
    w.x = f2bf(bf2f(sv.x) + bsv.x); w.y = f2bf(bf2f(sv.y) + bsv.y);
    w.z = f2bf(bf2f(sv.z) + bsv.z); w.w = f2bf(bf2f(sv.w) + bsv.w);
    *(ushort4*)(Yp + rb[i] + 3072 + e0) = w;
  }
}

// ---------- logits: out[r, c] = feats[r,:] . Wc[c,:] + bc[c]  (C=4, K=1024) ----------
__global__ __launch_bounds__(256) void logits_kernel(
    const float* __restrict__ feats, const float* __restrict__ Wc,
    const float* __restrict__ bc, float* __restrict__ out)
{
  __shared__ float w[4096];
  const int t = threadIdx.x;
  for (int i = t; i < 4096; i += 256) w[i] = Wc[i];
  __syncthreads();
  const int wave = t >> 6, l = t & 63;
  const int row = blockIdx.x * 4 + wave;
  const float* f = feats + (size_t)row * 1024;
  float s0 = 0.f, s1 = 0.f, s2 = 0.f, s3 = 0.f;
#pragma unroll
  for (int c4 = 0; c4 < 4; ++c4) {
    int e = c4 * 256 + l * 4;
    float4 x  = *(const float4*)(f + e);
    float4 w0 = *(const float4*)(w + e);
    float4 w1 = *(const float4*)(w + 1024 + e);
    float4 w2 = *(const float4*)(w + 2048 + e);
    float4 w3 = *(const float4*)(w + 3072 + e);
    s0 += x.x*w0.x + x.y*w0.y + x.z*w0.z + x.w*w0.w;
    s1 += x.x*w1.x + x.y*w1.y + x.z*w1.z + x.w*w1.w;
    s2 += x.x*w2.x + x.y*w2.y + x.z*w2.z + x.w*w2.w;
    s3 += x.x*w3.x + x.y*w3.y + x.z*w3.z + x.w*w3.w;
  }
#pragma unroll
  for (int d = 1; d < 64; d <<= 1) {
    s0 += __shfl_xor(s0, d); s1 += __shfl_xor(s1, d);
    s2 += __shfl_xor(s2, d); s3 += __shfl_xor(s3, d);
  }
  if (l < 4) {
    float s = (l == 0) ? s0 : (l == 1) ? s1 : (l == 2) ? s2 : s3;
    out[(size_t)row * 4 + l] = s + bc[l];
  }
}

// ---------- launch ----------
extern "C" void kernel_launch(void* const* d_in, const int* in_sizes, int n_in,
                              void* d_out, int out_size, void* d_ws, size_t ws_size,
                              hipStream_t stream) {
  const float* X1   = (const float*)d_in[0];
  const float* X2   = (const float*)d_in[1];
  const float* X3   = (const float*)d_in[2];
  const float* X4   = (const float*)d_in[3];
  const float* Wq   = (const float*)d_in[4];
  const float* bq   = (const float*)d_in[5];
  // d_in[6] Wk_s, d_in[7] bk_s: unused (softmax over a single key == identity)
  const float* Wv_s = (const float*)d_in[8];
  const float* bv_s = (const float*)d_in[9];
  const float* Wo_s = (const float*)d_in[10];
  const float* bo_s = (const float*)d_in[11];
  const float* Wk_c = (const float*)d_in[12];
  const float* bk_c = (const float*)d_in[13];
  const float* Wv_c = (const float*)d_in[14];
  const float* bv_c = (const float*)d_in[15];
  const float* Wo_c = (const float*)d_in[16];
  const float* bo_c = (const float*)d_in[17];
  const float* Wc   = (const float*)d_in[18];
  const float* bc   = (const float*)d_in[19];

  char* ws = (char*)d_ws;
  unsigned short* Xcat  = (unsigned short*)(ws + 0);
  unsigned short* Wcat  = (unsigned short*)(ws + 67108864);
  unsigned short* Wocat = (unsigned short*)(ws + 75497472);
  float*          biaso = (float*)        (ws + 79691776);
  unsigned short* Yproj = (unsigned short*)(ws + 79695872);
  float* out = (float*)d_out;

  convert_x<<<32768, 256, 0, stream>>>(X1, X2, X3, X4, Xcat);
  prep_w<<<6145, 256, 0, stream>>>(Wq, Wk_c, Wv_c, Wv_s, Wo_c, Wo_s, bo_c, bo_s,
                                   Wcat, Wocat, biaso);
  // Yproj[i*B+b, :] = [KcX | VcX | QX | VsX]
  gemm_bt<false, false><<<dim3(32, 256), 256, 0, stream>>>(
      Xcat, 1024, Wcat, 1024, (void*)Yproj, 4096, nullptr, 1024);
  attn_kernel<<<8192, 256, 0, stream>>>(Yproj, bq, bk_c, bv_c, bv_s);
  // d = [A | Vs'] @ [Wo_c | Wo_s]^T + (bo_c + bo_s)
  gemm_bt<true, true><<<dim3(8, 256), 256, 0, stream>>>(
      Yproj + 2048, 4096, Wocat, 2048, (void*)out, 1024, biaso, 2048);
  logits_kernel<<<8192, 256, 0, stream>>>(out, Wc, bc, out + 33554432);
}

// Round 2
// 819.004 us; speedup vs baseline: 1.1020x; 1.1020x over previous
//
#include <hip/hip_runtime.h>

// ---------- types & helpers ----------
typedef __bf16 bf16x8 __attribute__((ext_vector_type(8)));
typedef float f32x4 __attribute__((ext_vector_type(4)));

__device__ __forceinline__ float bf2f(unsigned short u) {
  union { unsigned int i; float f; } c; c.i = ((unsigned int)u) << 16; return c.f;
}
__device__ __forceinline__ unsigned short f2bf(float f) {
  union { float f; unsigned int i; } c; c.f = f;
  unsigned int u = c.i;
  u += 0x7FFFu + ((u >> 16) & 1u);   // RNE
  return (unsigned short)(u >> 16);
}

#define GLDS16(g, l)                                                          \
  __builtin_amdgcn_global_load_lds(                                           \
      (const __attribute__((address_space(1))) void*)(g),                     \
      (__attribute__((address_space(3))) void*)(l), 16, 0, 0)

// ---------- constants ----------
// B=8192, D=1024, H=4, hd=256, C=4
// Self path folded:  self_out = X @ (Wo_s·Wv_s)^T + (bv_s@Wo_s^T + bo_s)
// ws layout (bytes):
//  Xcat   bf16 [32768 x 1024]   @ 0          (64 MB)
//  Wcat   bf16 [3072 x 1024]    @ 67108864   (6 MB)   rows: [Wk_c | Wv_c | Wq]
//  WoM2   bf16 [1024 x 2048]    @ 73400320   (4 MB)   row n = [Wo_c[n,:], M2[n,:]]
//  Wos_bf bf16 [1024 x 1024]    @ 77594624   (2 MB)
//  WvsT   bf16 [1024 x 1024]    @ 79691776   (2 MB)   WvsT[k][j] = Wv_s[j][k]
//  bias2  f32  [1024]           @ 81788928
//  Yproj  bf16 [32768 x 3072]   @ 81793024   (192 MB) cols: [KcX | VcX | QX->A]

// ---------- convert X1..X4 -> bf16 Xcat ----------
__global__ __launch_bounds__(256) void convert_x(
    const float* __restrict__ X1, const float* __restrict__ X2,
    const float* __restrict__ X3, const float* __restrict__ X4,
    unsigned short* __restrict__ Xcat)
{
  int gid = blockIdx.x * 256 + threadIdx.x;          // 8388608 threads
  size_t base = (size_t)gid * 4;
  int sec = (int)(base >> 23);
  int off = (int)(base & 8388607);
  const float* s = sec == 0 ? X1 : sec == 1 ? X2 : sec == 2 ? X3 : X4;
  float4 v = *(const float4*)(s + off);
  ushort4 o;
  o.x = f2bf(v.x); o.y = f2bf(v.y); o.z = f2bf(v.z); o.w = f2bf(v.w);
  *(ushort4*)(Xcat + base) = o;
}

// ---------- prep weights ----------
__global__ __launch_bounds__(256) void prep_w(
    const float* __restrict__ Wq,  const float* __restrict__ Wk_c,
    const float* __restrict__ Wv_c, const float* __restrict__ Wo_c,
    const float* __restrict__ Wo_s,
    unsigned short* __restrict__ Wcat, unsigned short* __restrict__ WoM2,
    unsigned short* __restrict__ Wos_bf)
{
  int gid = blockIdx.x * 256 + threadIdx.x;
  if (gid < 786432) {                                // Wcat: 3 x 1M elements
    int base = gid * 4;
    int sec = base >> 20, off = base & 1048575;
    const float* s = sec == 0 ? Wk_c : sec == 1 ? Wv_c : Wq;
    float4 v = *(const float4*)(s + off);
    ushort4 o;
    o.x = f2bf(v.x); o.y = f2bf(v.y); o.z = f2bf(v.z); o.w = f2bf(v.w);
    *(ushort4*)(Wcat + base) = o;
  } else if (gid < 1048576) {                        // Wo_c -> WoM2 cols 0..1023
    int idx = (gid - 786432) * 4;
    int n = idx >> 10, c = idx & 1023;
    float4 v = *(const float4*)(Wo_c + (size_t)n * 1024 + c);
    ushort4 o;
    o.x = f2bf(v.x); o.y = f2bf(v.y); o.z = f2bf(v.z); o.w = f2bf(v.w);
    *(ushort4*)(WoM2 + (size_t)n * 2048 + c) = o;
  } else if (gid < 1310720) {                        // Wo_s -> bf16 (linear)
    int base = (gid - 1048576) * 4;
    float4 v = *(const float4*)(Wo_s + base);
    ushort4 o;
    o.x = f2bf(v.x); o.y = f2bf(v.y); o.z = f2bf(v.z); o.w = f2bf(v.w);
    *(ushort4*)(Wos_bf + base) = o;
  }
}

// ---------- transpose Wv_s -> WvsT (bf16) ----------
__global__ __launch_bounds__(256) void transpose_wvs(
    const float* __restrict__ Wv_s, unsigned short* __restrict__ WvsT)
{
  __shared__ float tile[32][33];
  const int r = threadIdx.x >> 3;          // 0..31
  const int c4 = (threadIdx.x & 7) * 4;    // 0,4,..,28
  const int j0 = blockIdx.y * 32, k0 = blockIdx.x * 32;
  float4 v = *(const float4*)(Wv_s + (size_t)(j0 + r) * 1024 + k0 + c4);
  tile[r][c4] = v.x; tile[r][c4 + 1] = v.y; tile[r][c4 + 2] = v.z; tile[r][c4 + 3] = v.w;
  __syncthreads();
  ushort4 o;
  o.x = f2bf(tile[c4 + 0][r]); o.y = f2bf(tile[c4 + 1][r]);
  o.z = f2bf(tile[c4 + 2][r]); o.w = f2bf(tile[c4 + 3][r]);
  *(ushort4*)(WvsT + (size_t)(k0 + r) * 1024 + j0 + c4) = o;
}

// ---------- bias2 = bo_c + bo_s + Wo_s @ bv_s ----------
__global__ __launch_bounds__(256) void bias2_kernel(
    const float* __restrict__ Wo_s, const float* __restrict__ bv_s,
    const float* __restrict__ bo_c, const float* __restrict__ bo_s,
    float* __restrict__ bias2)
{
  const int wv = threadIdx.x >> 6, l = threadIdx.x & 63;
  const int n = blockIdx.x * 4 + wv;
  const float* row = Wo_s + (size_t)n * 1024;
  float s = 0.f;
#pragma unroll
  for (int it = 0; it < 4; ++it) {
    int j = it * 256 + l * 4;
    float4 w = *(const float4*)(row + j);
    float4 b = *(const float4*)(bv_s + j);
    s += w.x * b.x + w.y * b.y + w.z * b.z + w.w * b.w;
  }
#pragma unroll
  for (int d = 1; d < 64; d <<= 1) s += __shfl_xor(s, d);
  if (l == 0) bias2[n] = s + bo_c[n] + bo_s[n];
}

// ---------- GEMM: C[M,N] = [A1 | A2][M,K1+K2] * Bw[N,K]^T (+bias) ----------
// 128x128 block tile, BK=32, 256 threads = 4 waves (2x2), 4x4 MFMA 16x16x32 each.
// XOR swizzle on 16B k-chunks: phys_chunk = kchunk ^ ((row>>1)&3) -> <=2-way LDS conflict (free).
template<bool OUT_F32, bool HAS_BIAS>
__global__ __launch_bounds__(256) void gemm_bt(
    const unsigned short* __restrict__ A1, int lda1, int K1,
    const unsigned short* __restrict__ A2, int lda2, int K2,
    const unsigned short* __restrict__ Bw, int ldb,
    void* __restrict__ Cout, int ldc,
    const float* __restrict__ bias)
{
  __shared__ char lds[16384];
  char* ldsA = lds;
  char* ldsB = lds + 8192;

  const int t = threadIdx.x;
  const int l = t & 63;
  const int wv = t >> 6;
  const int wr = wv >> 1, wc = wv & 1;
  const int bM = blockIdx.y * 128, bN = blockIdx.x * 128;

  // staging: 512 16B-chunks per operand tile (128 rows x 4 chunks), 2 insts x 256 thr
  const int pa0 = t, pa1 = t + 256;
  const int ra0 = pa0 >> 2, ra1 = pa1 >> 2;
  const int ca0 = (((pa0 & 3) ^ ((ra0 >> 1) & 3))) * 8;  // element offset in k
  const int ca1 = (((pa1 & 3) ^ ((ra1 >> 1) & 3))) * 8;
  const unsigned short* gB0 = Bw + (size_t)(bN + ra0) * ldb + ca0;
  const unsigned short* gB1 = Bw + (size_t)(bN + ra1) * ldb + ca1;
  char* lA0 = ldsA + pa0 * 16; char* lA1 = ldsA + pa1 * 16;
  char* lB0 = ldsB + pa0 * 16; char* lB1 = ldsB + pa1 * 16;

  // fragment read addressing
  const int rA = wr * 64 + (l & 15);
  const int rB = wc * 64 + (l & 15);
  const int cA = ((l >> 4) ^ ((rA >> 1) & 3)) * 16;   // byte offset within row
  const int cB = ((l >> 4) ^ ((rB >> 1) & 3)) * 16;
  const char* fA = ldsA + rA * 64 + cA;
  const char* fB = ldsB + rB * 64 + cB;

  f32x4 acc[4][4] = {};

  const unsigned short* gA0 = A1 + (size_t)(bM + ra0) * lda1 + ca0;
  const unsigned short* gA1 = A1 + (size_t)(bM + ra1) * lda1 + ca1;

  for (int src = 0; src < 2; ++src) {
    const int Kc = src ? K2 : K1;
    if (src) {
      if (K2 == 0) break;
      gA0 = A2 + (size_t)(bM + ra0) * lda2 + ca0;
      gA1 = A2 + (size_t)(bM + ra1) * lda2 + ca1;
    }
    for (int k0 = 0; k0 < Kc; k0 += 32) {
      GLDS16(gA0, lA0); GLDS16(gA1, lA1);
      GLDS16(gB0, lB0); GLDS16(gB1, lB1);
      gA0 += 32; gA1 += 32; gB0 += 32; gB1 += 32;
      __syncthreads();

      bf16x8 af[4], bf[4];
#pragma unroll
      for (int i = 0; i < 4; ++i) af[i] = *(const bf16x8*)(fA + i * 1024);
#pragma unroll
      for (int i = 0; i < 4; ++i) bf[i] = *(const bf16x8*)(fB + i * 1024);
#pragma unroll
      for (int mt = 0; mt < 4; ++mt)
#pragma unroll
        for (int nt = 0; nt < 4; ++nt)
          acc[mt][nt] = __builtin_amdgcn_mfma_f32_16x16x32_bf16(
              af[mt], bf[nt], acc[mt][nt], 0, 0, 0);
      __syncthreads();
    }
  }

  // epilogue: D row = (lane>>4)*4 + reg, col = lane&15  (verified m89/m91 layout)
  const int mrow = bM + wr * 64 + ((l >> 4) << 2);
  const int ncol = bN + wc * 64 + (l & 15);
  float bvals[4];
  if (HAS_BIAS) {
#pragma unroll
    for (int nt = 0; nt < 4; ++nt) bvals[nt] = bias[ncol + nt * 16];
  }
#pragma unroll
  for (int mt = 0; mt < 4; ++mt)
#pragma unroll
    for (int nt = 0; nt < 4; ++nt)
#pragma unroll
      for (int r = 0; r < 4; ++r) {
        size_t idx = (size_t)(mrow + mt * 16 + r) * ldc + (ncol + nt * 16);
        float v = acc[mt][nt][r];
        if (HAS_BIAS) v += bvals[nt];
        if (OUT_F32) ((float*)Cout)[idx] = v;
        else         ((unsigned short*)Cout)[idx] = f2bf(v);
      }
}

// ---------- attention (3 keys, 4 heads) ----------
// One block per b; wave = head; lane covers 4 contiguous dims of the head slice.
// Writes attn output over the QX slot.
__global__ __launch_bounds__(256) void attn_kernel(
    unsigned short* __restrict__ Yp,
    const float* __restrict__ bq,  const float* __restrict__ bkc,
    const float* __restrict__ bvc)
{
  const int b = blockIdx.x;
  const int h = threadIdx.x >> 6;
  const int l = threadIdx.x & 63;
  const int e0 = h * 256 + l * 4;

  const float4 bqv = *(const float4*)(bq + e0);
  const float4 bkv = *(const float4*)(bkc + e0);
  const float4 bvv = *(const float4*)(bvc + e0);

  float q[4][4], kc[4][4], vc[4][4];
  size_t rb[4];
#pragma unroll
  for (int i = 0; i < 4; ++i) {
    rb[i] = ((size_t)i * 8192 + b) * 3072;
    ushort4 qq = *(const ushort4*)(Yp + rb[i] + 2048 + e0);
    ushort4 kk = *(const ushort4*)(Yp + rb[i] + e0);
    ushort4 vv = *(const ushort4*)(Yp + rb[i] + 1024 + e0);
    q[i][0] = bf2f(qq.x) + bqv.x; q[i][1] = bf2f(qq.y) + bqv.y;
    q[i][2] = bf2f(qq.z) + bqv.z; q[i][3] = bf2f(qq.w) + bqv.w;
    kc[i][0] = bf2f(kk.x); kc[i][1] = bf2f(kk.y);
    kc[i][2] = bf2f(kk.z); kc[i][3] = bf2f(kk.w);
    vc[i][0] = bf2f(vv.x); vc[i][1] = bf2f(vv.y);
    vc[i][2] = bf2f(vv.z); vc[i][3] = bf2f(vv.w);
  }

  // partial dots: u[i][j] = Qi . KcXj  (head slice), tb[i] = Qi . bk_c
  float u[4][4], tb[4];
#pragma unroll
  for (int i = 0; i < 4; ++i) {
    tb[i] = q[i][0]*bkv.x + q[i][1]*bkv.y + q[i][2]*bkv.z + q[i][3]*bkv.w;
#pragma unroll
    for (int j = 0; j < 4; ++j)
      u[i][j] = q[i][0]*kc[j][0] + q[i][1]*kc[j][1] + q[i][2]*kc[j][2] + q[i][3]*kc[j][3];
  }
#pragma unroll
  for (int d = 1; d < 64; d <<= 1) {
#pragma unroll
    for (int i = 0; i < 4; ++i) {
      tb[i] += __shfl_xor(tb[i], d);
#pragma unroll
      for (int j = 0; j < 4; ++j) u[i][j] += __shfl_xor(u[i][j], d);
    }
  }

#pragma unroll
  for (int i = 0; i < 4; ++i) {
    // scores over the 3 other inputs: s_ij = (Qi.Kci - Qi.Kcj + Qi.bk) / 16
    float s[4], a[4];
    float mx = -1e30f;
#pragma unroll
    for (int j = 0; j < 4; ++j) {
      s[j] = (u[i][i] - u[i][j] + tb[i]) * 0.0625f;
      if (j != i) mx = fmaxf(mx, s[j]);
    }
    float den = 0.f;
#pragma unroll
    for (int j = 0; j < 4; ++j) {
      a[j] = (j == i) ? 0.f : __expf(s[j] - mx);
      den += a[j];
    }
    float inv = 1.f / den;
#pragma unroll
    for (int j = 0; j < 4; ++j) a[j] *= inv;

    // out = Vc_i + bv_c - sum_j a_j * Vc_j     (since sum a = 1)
    float o0 = vc[i][0] + bvv.x, o1 = vc[i][1] + bvv.y;
    float o2 = vc[i][2] + bvv.z, o3 = vc[i][3] + bvv.w;
#pragma unroll
    for (int j = 0; j < 4; ++j) {
      o0 -= a[j] * vc[j][0]; o1 -= a[j] * vc[j][1];
      o2 -= a[j] * vc[j][2]; o3 -= a[j] * vc[j][3];
    }
    ushort4 w;
    w.x = f2bf(o0); w.y = f2bf(o1); w.z = f2bf(o2); w.w = f2bf(o3);
    *(ushort4*)(Yp + rb[i] + 2048 + e0) = w;   // overwrite Q slot (same thread owns it)
  }
}

// ---------- logits: out[r, c] = feats[r,:] . Wc[c,:] + bc[c]  (C=4, K=1024) ----------
__global__ __launch_bounds__(256) void logits_kernel(
    const float* __restrict__ feats, const float* __restrict__ Wc,
    const float* __restrict__ bc, float* __restrict__ out)
{
  __shared__ float w[4096];
  const int t = threadIdx.x;
  for (int i = t; i < 4096; i += 256) w[i] = Wc[i];
  __syncthreads();
  const int wave = t >> 6, l = t & 63;
  const int row = blockIdx.x * 4 + wave;
  const float* f = feats + (size_t)row * 1024;
  float s0 = 0.f, s1 = 0.f, s2 = 0.f, s3 = 0.f;
#pragma unroll
  for (int c4 = 0; c4 < 4; ++c4) {
    int e = c4 * 256 + l * 4;
    float4 x  = *(const float4*)(f + e);
    float4 w0 = *(const float4*)(w + e);
    float4 w1 = *(const float4*)(w + 1024 + e);
    float4 w2 = *(const float4*)(w + 2048 + e);
    float4 w3 = *(const float4*)(w + 3072 + e);
    s0 += x.x*w0.x + x.y*w0.y + x.z*w0.z + x.w*w0.w;
    s1 += x.x*w1.x + x.y*w1.y + x.z*w1.z + x.w*w1.w;
    s2 += x.x*w2.x + x.y*w2.y + x.z*w2.z + x.w*w2.w;
    s3 += x.x*w3.x + x.y*w3.y + x.z*w3.z + x.w*w3.w;
  }
#pragma unroll
  for (int d = 1; d < 64; d <<= 1) {
    s0 += __shfl_xor(s0, d); s1 += __shfl_xor(s1, d);
    s2 += __shfl_xor(s2, d); s3 += __shfl_xor(s3, d);
  }
  if (l < 4) {
    float s = (l == 0) ? s0 : (l == 1) ? s1 : (l == 2) ? s2 : s3;
    out[(size_t)row * 4 + l] = s + bc[l];
  }
}

// ---------- launch ----------
extern "C" void kernel_launch(void* const* d_in, const int* in_sizes, int n_in,
                              void* d_out, int out_size, void* d_ws, size_t ws_size,
                              hipStream_t stream) {
  const float* X1   = (const float*)d_in[0];
  const float* X2   = (const float*)d_in[1];
  const float* X3   = (const float*)d_in[2];
  const float* X4   = (const float*)d_in[3];
  const float* Wq   = (const float*)d_in[4];
  const float* bq   = (const float*)d_in[5];
  // d_in[6] Wk_s, d_in[7] bk_s: unused (softmax over a single key == identity)
  const float* Wv_s = (const float*)d_in[8];
  const float* bv_s = (const float*)d_in[9];
  const float* Wo_s = (const float*)d_in[10];
  const float* bo_s = (const float*)d_in[11];
  const float* Wk_c = (const float*)d_in[12];
  const float* bk_c = (const float*)d_in[13];
  const float* Wv_c = (const float*)d_in[14];
  const float* bv_c = (const float*)d_in[15];
  const float* Wo_c = (const float*)d_in[16];
  const float* bo_c = (const float*)d_in[17];
  const float* Wc   = (const float*)d_in[18];
  const float* bc   = (const float*)d_in[19];

  char* ws = (char*)d_ws;
  unsigned short* Xcat   = (unsigned short*)(ws + 0);
  unsigned short* Wcat   = (unsigned short*)(ws + 67108864);
  unsigned short* WoM2   = (unsigned short*)(ws + 73400320);
  unsigned short* Wos_bf = (unsigned short*)(ws + 77594624);
  unsigned short* WvsT   = (unsigned short*)(ws + 79691776);
  float*          bias2  = (float*)        (ws + 81788928);
  unsigned short* Yproj  = (unsigned short*)(ws + 81793024);
  float* out = (float*)d_out;

  convert_x<<<32768, 256, 0, stream>>>(X1, X2, X3, X4, Xcat);
  prep_w<<<5120, 256, 0, stream>>>(Wq, Wk_c, Wv_c, Wo_c, Wo_s, Wcat, WoM2, Wos_bf);
  transpose_wvs<<<dim3(32, 32), 256, 0, stream>>>(Wv_s, WvsT);
  bias2_kernel<<<256, 256, 0, stream>>>(Wo_s, bv_s, bo_c, bo_s, bias2);
  // M2 = Wo_s @ Wv_s  -> WoM2 cols 1024..2047
  gemm_bt<false, false><<<dim3(8, 8), 256, 0, stream>>>(
      Wos_bf, 1024, 1024, nullptr, 0, 0, WvsT, 1024,
      (void*)(WoM2 + 1024), 2048, nullptr);
  // Yproj[i*B+b, :] = [KcX | VcX | QX]
  gemm_bt<false, false><<<dim3(24, 256), 256, 0, stream>>>(
      Xcat, 1024, 1024, nullptr, 0, 0, Wcat, 1024,
      (void*)Yproj, 3072, nullptr);
  attn_kernel<<<8192, 256, 0, stream>>>(Yproj, bq, bk_c, bv_c);
  // d = [A | X] @ [Wo_c | M2]^T + bias2
  gemm_bt<true, true><<<dim3(8, 256), 256, 0, stream>>>(
      Yproj + 2048, 3072, 1024, Xcat, 1024, 1024, WoM2, 2048,
      (void*)out, 1024, bias2);
  logits_kernel<<<8192, 256, 0, stream>>>(out, Wc, bc, out + 33554432);
}